// Round 1
// baseline (5319.801 us; speedup 1.0000x reference)
//
#include <hip/hip_runtime.h>
#include <math.h>

// Problem constants (from reference)
#define S_LEN 4096
#define EMB   2048
#define NH    16
#define NKV   4
#define HD    128
#define WIN   512
#define META  16
#define BATCH 2
#define KV_N  (2*NKV*HD)   // 1024

// ---------------------------------------------------------------------------
// Tiled fp32 GEMM: C[M,N] = A[M,K] @ W[K,N] + bias, with fused epilogues.
// MODE 0: Q projection -> RoPE -> Qr[(b*NH+h)*S + s][d]
// MODE 1: KV projection -> K gets RoPE -> Kr[(b*NKV+kvh)*S+s][d], V plain -> Vr
// MODE 2: plain + bias -> out[r*N + c]
// BM=BN=128, BK=16, 256 threads, 8x8 micro-tile per thread.
// ---------------------------------------------------------------------------
template<int MODE>
__global__ __launch_bounds__(256)
void gemm_epi(const float* __restrict__ A, const float* __restrict__ W,
              const float* __restrict__ bias,
              float* __restrict__ out0, float* __restrict__ out1,
              int M, int N, int K)
{
    constexpr int BM = 128, BN = 128, BK = 16;
    __shared__ float As[BK][BM];   // stored transposed: As[k][m]
    __shared__ float Bs[BK][BN];

    const int tid  = threadIdx.x;
    const int bm   = blockIdx.y, bn = blockIdx.x;
    const int row0 = bm * BM, col0 = bn * BN;
    const int tm0  = (tid >> 4) << 3;   // 0..120
    const int tn0  = (tid & 15) << 3;   // 0..120

    float acc[8][8];
    #pragma unroll
    for (int i = 0; i < 8; i++)
        #pragma unroll
        for (int j = 0; j < 8; j++) acc[i][j] = 0.f;

    const float* Aptr = A + (size_t)row0 * K;
    const float* Wptr = W + col0;

    for (int kt = 0; kt < K; kt += BK) {
        // Load A tile (128 rows x 16 cols), store transposed.
        #pragma unroll
        for (int i = 0; i < 2; i++) {
            int f  = i * 256 + tid;      // 512 float4 total
            int r  = f >> 2, c4 = f & 3;
            float4 v = *(const float4*)(Aptr + (size_t)r * K + kt + c4 * 4);
            As[c4*4+0][r] = v.x; As[c4*4+1][r] = v.y;
            As[c4*4+2][r] = v.z; As[c4*4+3][r] = v.w;
        }
        // Load W tile (16 rows x 128 cols), direct.
        #pragma unroll
        for (int i = 0; i < 2; i++) {
            int f  = i * 256 + tid;
            int r  = f >> 5, c4 = f & 31;
            float4 v = *(const float4*)(Wptr + (size_t)(kt + r) * N + c4 * 4);
            *(float4*)&Bs[r][c4*4] = v;
        }
        __syncthreads();

        #pragma unroll
        for (int k = 0; k < BK; k++) {
            float a[8], b[8];
            *(float4*)&a[0] = *(const float4*)&As[k][tm0];
            *(float4*)&a[4] = *(const float4*)&As[k][tm0 + 4];
            *(float4*)&b[0] = *(const float4*)&Bs[k][tn0];
            *(float4*)&b[4] = *(const float4*)&Bs[k][tn0 + 4];
            #pragma unroll
            for (int i = 0; i < 8; i++)
                #pragma unroll
                for (int j = 0; j < 8; j++)
                    acc[i][j] = fmaf(a[i], b[j], acc[i][j]);
        }
        __syncthreads();
    }

    // ------------------------- epilogues -------------------------
    if (MODE == 2) {
        #pragma unroll
        for (int i = 0; i < 8; i++) {
            int r = row0 + tm0 + i;
            float* dst = out0 + (size_t)r * N + col0 + tn0;
            #pragma unroll
            for (int j = 0; j < 8; j += 4) {
                int c = col0 + tn0 + j;
                float4 v;
                v.x = acc[i][j+0] + bias[c+0];
                v.y = acc[i][j+1] + bias[c+1];
                v.z = acc[i][j+2] + bias[c+2];
                v.w = acc[i][j+3] + bias[c+3];
                *(float4*)(dst + j) = v;
            }
        }
        return;
    }

    #pragma unroll
    for (int i = 0; i < 8; i++) {
        int r  = row0 + tm0 + i;
        int s  = r & (S_LEN - 1);
        int bb = r >> 12;            // S_LEN = 4096 = 2^12
        float pos = (float)s;
        #pragma unroll
        for (int j = 0; j < 8; j += 2) {
            int c  = col0 + tn0 + j;
            float v0 = acc[i][j]   + bias[c];
            float v1 = acc[i][j+1] + bias[c+1];
            if (MODE == 0) {
                // Q: every column gets RoPE.  head = c/128, d = c%128 (even)
                int head = c >> 7;
                int d    = c & 127;
                float inv = 1.0f / powf(10000.0f, (float)d * (1.0f / 128.0f));
                float ang = pos * inv;
                float sn, cs; sincosf(ang, &sn, &cs);
                float o0 = v0 * cs - v1 * sn;
                float o1 = v1 * cs + v0 * sn;
                float* dst = out0 + (((size_t)(bb * NH + head) * S_LEN + s) * HD + d);
                dst[0] = o0; dst[1] = o1;
            } else { // MODE 1 : KV
                int t2  = c >> 9;           // 0 = K, 1 = V   (KVH*HD = 512)
                int kvh = (c >> 7) & 3;
                int d   = c & 127;
                if (t2 == 0) {
                    float inv = 1.0f / powf(10000.0f, (float)d * (1.0f / 128.0f));
                    float ang = pos * inv;
                    float sn, cs; sincosf(ang, &sn, &cs);
                    float o0 = v0 * cs - v1 * sn;
                    float o1 = v1 * cs + v0 * sn;
                    float* dst = out0 + (((size_t)(bb * NKV + kvh) * S_LEN + s) * HD + d);
                    dst[0] = o0; dst[1] = o1;
                } else {
                    float* dst = out1 + (((size_t)(bb * NKV + kvh) * S_LEN + s) * HD + d);
                    dst[0] = v0; dst[1] = v1;
                }
            }
        }
    }
}

// ---------------------------------------------------------------------------
// Flash-style sliding-window attention with sink tokens.
// Grid: (S/32, NH, B).  Block: 256 threads.
// Per block: 32 queries.  Thread (qrow=tid>>3, l8=tid&7):
//   - scores: 4 keys per thread per 32-key tile
//   - output: 16 dims per thread (d0 = l8*16)
// Layouts: Q[(b*NH+h)*S+s][128], K/V[(b*NKV+kvh)*S+s][128], Y[b][s][h*128+d]
// ---------------------------------------------------------------------------
__global__ __launch_bounds__(256)
void attn_k(const float* __restrict__ Q, const float* __restrict__ K,
            const float* __restrict__ V, float* __restrict__ Y)
{
    constexpr int QT = 32, LSTRIDE = 132;
    __shared__ float Qs[QT][LSTRIDE];
    __shared__ float Ks[QT][LSTRIDE];
    __shared__ float Vs[QT][LSTRIDE];
    __shared__ float Ps[QT][36];

    const int tid  = threadIdx.x;
    const int qrow = tid >> 3;
    const int l8   = tid & 7;
    const int qs   = blockIdx.x * QT;
    const int h    = blockIdx.y;
    const int b    = blockIdx.z;
    const int kvh  = h >> 2;            // rep = NH/NKV = 4

    const float* Qbase = Q + ((size_t)(b * NH  + h)   * S_LEN + qs) * HD;
    const float* Kbase = K +  (size_t)(b * NKV + kvh) * S_LEN * HD;
    const float* Vbase = V +  (size_t)(b * NKV + kvh) * S_LEN * HD;

    // Load Q tile: 32x128 = 1024 float4
    #pragma unroll
    for (int i = 0; i < 4; i++) {
        int f = i * 256 + tid;
        int r = f >> 5, c4 = f & 31;
        *(float4*)&Qs[r][c4*4] = *(const float4*)(Qbase + (size_t)r * HD + c4 * 4);
    }

    const int qp = qs + qrow;
    const float scale = 0.08838834764831845f;   // 1/sqrt(128)
    float m = -1e30f, l = 0.f;
    float o[16];
    #pragma unroll
    for (int d = 0; d < 16; d++) o[d] = 0.f;

    // Tile list: tile 0 (sink), then max(1,(qs-511)/32) .. qs/32
    int ktlo = qs - WIN + 1;
    ktlo = (ktlo < 32) ? 1 : (ktlo >> 5);
    const int kthi = qs >> 5;

    int kt = 0;
    bool first = true;
    while (true) {
        const int kb = kt * QT;
        __syncthreads();   // protect Ks/Vs (prev PV) before overwrite
        #pragma unroll
        for (int i = 0; i < 4; i++) {
            int f = i * 256 + tid;
            int r = f >> 5, c4 = f & 31;
            *(float4*)&Ks[r][c4*4] = *(const float4*)(Kbase + (size_t)(kb + r) * HD + c4 * 4);
            *(float4*)&Vs[r][c4*4] = *(const float4*)(Vbase + (size_t)(kb + r) * HD + c4 * 4);
        }
        __syncthreads();

        // scores: 4 keys per thread
        float sc[4] = {0.f, 0.f, 0.f, 0.f};
        for (int k = 0; k < HD; k += 4) {
            float4 qv = *(const float4*)&Qs[qrow][k];
            #pragma unroll
            for (int jj = 0; jj < 4; jj++) {
                float4 kv = *(const float4*)&Ks[l8*4 + jj][k];
                sc[jj] += qv.x*kv.x + qv.y*kv.y + qv.z*kv.z + qv.w*kv.w;
            }
        }
        #pragma unroll
        for (int jj = 0; jj < 4; jj++) {
            int kp = kb + l8 * 4 + jj;
            bool allowed = (kp <= qp) && ((kp >= qp - (WIN - 1)) || (kp < META));
            sc[jj] = allowed ? sc[jj] * scale : -1e30f;
        }
        // row max over this thread's 4 + 8-thread group
        float tmax = fmaxf(fmaxf(sc[0], sc[1]), fmaxf(sc[2], sc[3]));
        #pragma unroll
        for (int off = 1; off < 8; off <<= 1)
            tmax = fmaxf(tmax, __shfl_xor(tmax, off));
        float mnew = fmaxf(m, tmax);
        float psum = 0.f;
        #pragma unroll
        for (int jj = 0; jj < 4; jj++) {
            sc[jj] = expf(sc[jj] - mnew);   // masked (-1e30) -> 0
            psum += sc[jj];
        }
        #pragma unroll
        for (int off = 1; off < 8; off <<= 1)
            psum += __shfl_xor(psum, off);
        float alpha = expf(m - mnew);
        l = l * alpha + psum;
        m = mnew;
        #pragma unroll
        for (int d = 0; d < 16; d++) o[d] *= alpha;

        #pragma unroll
        for (int jj = 0; jj < 4; jj++) Ps[qrow][l8*4 + jj] = sc[jj];
        __syncthreads();

        const int d0 = l8 * 16;
        for (int j = 0; j < QT; j++) {
            float p = Ps[qrow][j];
            const float4* vrow = (const float4*)&Vs[j][d0];
            #pragma unroll
            for (int q4 = 0; q4 < 4; q4++) {
                float4 v = vrow[q4];
                o[q4*4+0] = fmaf(p, v.x, o[q4*4+0]);
                o[q4*4+1] = fmaf(p, v.y, o[q4*4+1]);
                o[q4*4+2] = fmaf(p, v.z, o[q4*4+2]);
                o[q4*4+3] = fmaf(p, v.w, o[q4*4+3]);
            }
        }

        if (first) { kt = ktlo; first = false; } else { kt++; }
        if (kt > kthi) break;
    }

    // write Y[b][s][h*128+d]
    const float inv_l = 1.0f / l;
    float* yp = Y + ((size_t)b * S_LEN + qp) * EMB + h * HD + l8 * 16;
    #pragma unroll
    for (int q4 = 0; q4 < 4; q4++) {
        float4 v;
        v.x = o[q4*4+0] * inv_l; v.y = o[q4*4+1] * inv_l;
        v.z = o[q4*4+2] * inv_l; v.w = o[q4*4+3] * inv_l;
        *(float4*)(yp + q4*4) = v;
    }
}

// ---------------------------------------------------------------------------
extern "C" void kernel_launch(void* const* d_in, const int* in_sizes, int n_in,
                              void* d_out, int out_size, void* d_ws, size_t ws_size,
                              hipStream_t stream)
{
    const float* x   = (const float*)d_in[0];
    const float* Wq  = (const float*)d_in[1];
    const float* bq  = (const float*)d_in[2];
    const float* Wkv = (const float*)d_in[3];
    const float* bkv = (const float*)d_in[4];
    const float* Wo  = (const float*)d_in[5];
    const float* bo  = (const float*)d_in[6];
    float* out = (float*)d_out;

    const int M = BATCH * S_LEN;          // 8192
    // workspace layout (floats): Qr | Kr | Vr | Y  (needs ~168 MB)
    float* Qr = (float*)d_ws;
    float* Kr = Qr + (size_t)BATCH * NH  * S_LEN * HD;   // 16,777,216
    float* Vr = Kr + (size_t)BATCH * NKV * S_LEN * HD;   //  4,194,304
    float* Y  = Vr + (size_t)BATCH * NKV * S_LEN * HD;   //  4,194,304

    // Q projection + RoPE
    gemm_epi<0><<<dim3(EMB / 128, M / 128), 256, 0, stream>>>(
        x, Wq, bq, Qr, nullptr, M, EMB, EMB);
    // KV projection (+RoPE on K)
    gemm_epi<1><<<dim3(KV_N / 128, M / 128), 256, 0, stream>>>(
        x, Wkv, bkv, Kr, Vr, M, KV_N, EMB);
    // attention
    attn_k<<<dim3(S_LEN / 32, NH, BATCH), 256, 0, stream>>>(Qr, Kr, Vr, Y);
    // output projection
    gemm_epi<2><<<dim3(EMB / 128, M / 128), 256, 0, stream>>>(
        Y, Wo, bo, out, nullptr, M, EMB, EMB);
}

// Round 8
// 1570.189 us; speedup vs baseline: 3.3880x; 3.3880x over previous
//
#include <hip/hip_runtime.h>
#include <math.h>

// Problem constants
#define S_LEN 4096
#define EMB   2048
#define NH    16
#define NKV   4
#define HD    128
#define WIN   512
#define META  16
#define BATCH 2

typedef __attribute__((ext_vector_type(8))) short sh8;    // 8 bf16 (4 VGPR) MFMA frag
typedef __attribute__((ext_vector_type(4))) float f32x4;  // MFMA acc frag

__device__ __forceinline__ unsigned short f2bf(float f) {  // fp32 -> bf16 RNE
    unsigned u = __float_as_uint(f);
    return (unsigned short)((u + 0x7FFFu + ((u >> 16) & 1u)) >> 16);
}
__device__ __forceinline__ float bf2f(unsigned short s) {
    return __uint_as_float(((unsigned)s) << 16);
}

// ---------------------------------------------------------------------------
// RoPE cos/sin table: [4096][64] each. angle(s,i) = s * 10000^(-i/64)
// ---------------------------------------------------------------------------
__global__ void rope_tab_k(float* __restrict__ tc, float* __restrict__ ts) {
    int idx = blockIdx.x * 256 + threadIdx.x;      // 0..262143
    int s = idx >> 6, i = idx & 63;
    float inv = exp2f(-(float)i * 0.2076205059304601f);  // log2(1e4)/64
    float ang = (float)s * inv;
    tc[idx] = cosf(ang);
    ts[idx] = sinf(ang);
}

// ---------------------------------------------------------------------------
// Elementwise split fp32 -> bf16 hi + bf16 lo (same layout).
// ---------------------------------------------------------------------------
__global__ void split2_k(const float* __restrict__ in, short* __restrict__ hi,
                         short* __restrict__ lo, int n4) {
    int idx = blockIdx.x * 256 + threadIdx.x;
    if (idx >= n4) return;
    float4 v = ((const float4*)in)[idx];
    unsigned short h0 = f2bf(v.x), h1 = f2bf(v.y), h2 = f2bf(v.z), h3 = f2bf(v.w);
    short4 h = make_short4((short)h0, (short)h1, (short)h2, (short)h3);
    short4 l = make_short4((short)f2bf(v.x - bf2f(h0)), (short)f2bf(v.y - bf2f(h1)),
                           (short)f2bf(v.z - bf2f(h2)), (short)f2bf(v.w - bf2f(h3)));
    ((short4*)hi)[idx] = h;
    ((short4*)lo)[idx] = l;
}

// ---------------------------------------------------------------------------
// W [K=2048][N] fp32  ->  Wt hi/lo bf16 [N][2048]  (transpose + split)
// ---------------------------------------------------------------------------
__global__ void wsplit_t_k(const float* __restrict__ W, short* __restrict__ Th,
                           short* __restrict__ Tl, int N) {
    __shared__ float tile[32][33];
    int tx = threadIdx.x & 31, ty = threadIdx.x >> 5;
    int n0 = blockIdx.x * 32, k0 = blockIdx.y * 32;
    #pragma unroll
    for (int j = 0; j < 4; j++)
        tile[ty + 8*j][tx] = W[(size_t)(k0 + ty + 8*j) * N + n0 + tx];
    __syncthreads();
    #pragma unroll
    for (int j = 0; j < 4; j++) {
        int nn = ty + 8*j;
        float v = tile[tx][nn];                    // = W[k0+tx][n0+nn]
        unsigned short h = f2bf(v);
        size_t o = (size_t)(n0 + nn) * 2048 + k0 + tx;
        Th[o] = (short)h;
        Tl[o] = (short)f2bf(v - bf2f(h));
    }
}

// ---------------------------------------------------------------------------
// Split-bf16 MFMA GEMM:  C[M,N] = (Ah+Al) @ (Bh+Bl)^T + bias, fused epilogues.
// A: bf16 [M][2048] (hi/lo), B: bf16 [N][2048] (hi/lo, pre-transposed).
// C = Ah*Bh + Ah*Bl + Al*Bh (per-term error ~2^-18 rel; fp32-class).
// Tile 128x128, BK=32, 256 thr = 4 waves (2x2), 4x4 16x16x32 frags/wave.
// LDS as 16B chunks [row*4 + (kb ^ (row&3))]  -> conflict-free reads+writes.
// MODE 0: +RoPE -> Qr[(b*16+h)*4096+s][128]
// MODE 1: cols<512: K +RoPE -> Kr[(b*4+kvh)*4096+s][128]; cols>=512: V -> Vr
// MODE 2: plain -> out[r][2048]
// ---------------------------------------------------------------------------
template<int MODE>
__global__ __launch_bounds__(256)
void gemm_mfma(const short* __restrict__ Ah, const short* __restrict__ Al,
               const short* __restrict__ Bh, const short* __restrict__ Bl,
               const float* __restrict__ bias,
               const float* __restrict__ tabc, const float* __restrict__ tabs,
               float* __restrict__ out0, float* __restrict__ out1)
{
    __shared__ sh8 AsH[512], AsL[512], BsH[512], BsL[512];   // 4 x 8KB

    const int tid  = threadIdx.x;
    const int row0 = blockIdx.y * 128, col0 = blockIdx.x * 128;
    const int lane = tid & 63, wid = tid >> 6;
    const int wr = wid >> 1, wc = wid & 1;
    const int l15 = lane & 15, kb = lane >> 4;

    f32x4 acc[4][4];
    #pragma unroll
    for (int i = 0; i < 4; i++)
        #pragma unroll
        for (int j = 0; j < 4; j++) acc[i][j] = (f32x4){0.f, 0.f, 0.f, 0.f};

    // staging assignment: chunk jc (16B of 8 bf16), row rr and rr+64
    const int jc = tid & 3;
    const int rr = tid >> 2;                 // 0..63
    const int slot0 = rr * 4 + (jc ^ (rr & 3));
    const int slot1 = (rr + 64) * 4 + (jc ^ (rr & 3));   // (rr+64)&3 == rr&3

    #pragma unroll 1
    for (int kt = 0; kt < 2048; kt += 32) {
        size_t a0 = (size_t)(row0 + rr) * 2048 + kt + jc * 8;
        size_t a1 = a0 + (size_t)64 * 2048;
        size_t b0 = (size_t)(col0 + rr) * 2048 + kt + jc * 8;
        size_t b1 = b0 + (size_t)64 * 2048;
        sh8 vA0h = *(const sh8*)(Ah + a0);
        sh8 vA0l = *(const sh8*)(Al + a0);
        sh8 vA1h = *(const sh8*)(Ah + a1);
        sh8 vA1l = *(const sh8*)(Al + a1);
        sh8 vB0h = *(const sh8*)(Bh + b0);
        sh8 vB0l = *(const sh8*)(Bl + b0);
        sh8 vB1h = *(const sh8*)(Bh + b1);
        sh8 vB1l = *(const sh8*)(Bl + b1);
        __syncthreads();                      // prev compute done with LDS
        AsH[slot0] = vA0h; AsL[slot0] = vA0l;
        AsH[slot1] = vA1h; AsL[slot1] = vA1l;
        BsH[slot0] = vB0h; BsL[slot0] = vB0l;
        BsH[slot1] = vB1h; BsL[slot1] = vB1l;
        __syncthreads();

        sh8 fah[4], fal[4], fbh[4], fbl[4];
        #pragma unroll
        for (int i = 0; i < 4; i++) {
            int r  = wr * 64 + i * 16 + l15;
            int sl = r * 4 + (kb ^ (r & 3));
            fah[i] = AsH[sl]; fal[i] = AsL[sl];
            r  = wc * 64 + i * 16 + l15;
            sl = r * 4 + (kb ^ (r & 3));
            fbh[i] = BsH[sl]; fbl[i] = BsL[sl];
        }
        #pragma unroll
        for (int i = 0; i < 4; i++)
            #pragma unroll
            for (int j = 0; j < 4; j++) {
                acc[i][j] = __builtin_amdgcn_mfma_f32_16x16x32_bf16(fah[i], fbh[j], acc[i][j], 0, 0, 0);
                acc[i][j] = __builtin_amdgcn_mfma_f32_16x16x32_bf16(fah[i], fbl[j], acc[i][j], 0, 0, 0);
                acc[i][j] = __builtin_amdgcn_mfma_f32_16x16x32_bf16(fal[i], fbh[j], acc[i][j], 0, 0, 0);
            }
    }

    // ---- epilogue ----  C/D map: col = lane&15, row = (lane>>4)*4 + e  (m89-verified)
    const int gr_b = row0 + wr * 64 + (kb << 2);
    const int gc_b = col0 + wc * 64 + l15;
    #pragma unroll
    for (int i = 0; i < 4; i++) {
        #pragma unroll
        for (int j = 0; j < 4; j++) {
            f32x4 a = acc[i][j];
            const int gc = gc_b + j * 16;
            const float bs = bias[gc];
            #pragma unroll
            for (int e = 0; e < 4; e++) {
                const int gr = gr_b + i * 16 + e;
                float v = a[e] + bs;
                if (MODE == 2) {
                    out0[(size_t)gr * 2048 + gc] = v;
                } else {
                    const int s = gr & 4095, bb = gr >> 12;
                    const int d = gc & 127;
                    if (MODE == 0) {
                        const int ti = (s << 6) + (d >> 1);
                        float cs = tabc[ti], sn = tabs[ti];
                        float p = __shfl_xor(v, 1);
                        float o = (d & 1) ? fmaf(v, cs, p * sn) : fmaf(v, cs, -p * sn);
                        const int head = gc >> 7;
                        out0[((size_t)(bb * 16 + head) * 4096 + s) * 128 + d] = o;
                    } else {                  // MODE 1
                        if (gc < 512) {       // frag-uniform branch
                            const int ti = (s << 6) + (d >> 1);
                            float cs = tabc[ti], sn = tabs[ti];
                            float p = __shfl_xor(v, 1);
                            float o = (d & 1) ? fmaf(v, cs, p * sn) : fmaf(v, cs, -p * sn);
                            const int kvh = gc >> 7;
                            out0[((size_t)(bb * 4 + kvh) * 4096 + s) * 128 + d] = o;
                        } else {
                            const int kvh = (gc >> 7) & 3;
                            out1[((size_t)(bb * 4 + kvh) * 4096 + s) * 128 + d] = v;
                        }
                    }
                }
            }
        }
    }
}

// ---------------------------------------------------------------------------
// Register-blocked flash attention (R1 structure), emitting Yh/Yl bf16.
// Grid: (S/64, NH, B). Block: 256. Tile 64q x 32k.
// Thread (qg=tid>>4, tk=tid&15): QK rows {qg+16i} x keys {tk,tk+16};
// softmax state per-row in registers; PV rows {qg+16i} x dims {tk*4, 64+tk*4}.
// ---------------------------------------------------------------------------
__global__ __launch_bounds__(256, 2)
void attn_k(const float* __restrict__ Q, const float* __restrict__ K,
            const float* __restrict__ V, short* __restrict__ Yh,
            short* __restrict__ Yl)
{
    constexpr int QT = 64, KT = 32;
    constexpr int LQS = 132, LPS = 36;
    __shared__ float Qs[QT][LQS];
    __shared__ float Ks[KT][LQS];
    __shared__ float Vs[KT][LQS];
    __shared__ float Ps[QT][LPS];

    const int tid = threadIdx.x;
    const int qg  = tid >> 4;
    const int tk  = tid & 15;
    const int qs  = blockIdx.x * QT;
    const int h   = blockIdx.y;
    const int b   = blockIdx.z;
    const int kvh = h >> 2;

    const float* Qbase = Q + ((size_t)(b * NH  + h)   * S_LEN + qs) * HD;
    const float* Kbase = K +  (size_t)(b * NKV + kvh) * S_LEN * HD;
    const float* Vbase = V +  (size_t)(b * NKV + kvh) * S_LEN * HD;

    #pragma unroll
    for (int i = 0; i < 8; i++) {
        int f = i * 256 + tid;
        int r = f >> 5, c4 = f & 31;
        *(float4*)&Qs[r][c4*4] = *(const float4*)(Qbase + (size_t)r * HD + c4 * 4);
    }

    float m[4], l[4], o[4][8];
    #pragma unroll
    for (int i = 0; i < 4; i++) {
        m[i] = -1e30f; l[i] = 0.f;
        #pragma unroll
        for (int d = 0; d < 8; d++) o[i][d] = 0.f;
    }

    const float scale = 0.08838834764831845f;

    int lo2  = qs - WIN + 1;
    int ktlo = (lo2 < KT) ? 1 : (lo2 >> 5);
    const int kthi = (qs >> 5) + 1;

    int kt = 0;
    bool first = true;
    while (true) {
        const int kb = kt * KT;
        __syncthreads();
        #pragma unroll
        for (int i = 0; i < 4; i++) {
            int f = i * 256 + tid;
            int r = f >> 5, c4 = f & 31;
            *(float4*)&Ks[r][c4*4] = *(const float4*)(Kbase + (size_t)(kb + r) * HD + c4 * 4);
            *(float4*)&Vs[r][c4*4] = *(const float4*)(Vbase + (size_t)(kb + r) * HD + c4 * 4);
        }
        __syncthreads();

        float sc0[4] = {0.f,0.f,0.f,0.f}, sc1[4] = {0.f,0.f,0.f,0.f};
        #pragma unroll 8
        for (int k4 = 0; k4 < 32; k4++) {
            float4 ka = *(const float4*)&Ks[tk]     [k4*4];
            float4 kc = *(const float4*)&Ks[tk + 16][k4*4];
            #pragma unroll
            for (int i = 0; i < 4; i++) {
                float4 qv = *(const float4*)&Qs[qg + 16*i][k4*4];
                sc0[i] += qv.x*ka.x + qv.y*ka.y + qv.z*ka.z + qv.w*ka.w;
                sc1[i] += qv.x*kc.x + qv.y*kc.y + qv.z*kc.z + qv.w*kc.w;
            }
        }

        float alpha[4];
        const int kp0 = kb + tk, kp1 = kb + tk + 16;
        #pragma unroll
        for (int i = 0; i < 4; i++) {
            const int qp = qs + qg + 16*i;
            bool a0 = (kp0 <= qp) && ((kp0 >= qp - (WIN-1)) || (kp0 < META));
            bool a1 = (kp1 <= qp) && ((kp1 >= qp - (WIN-1)) || (kp1 < META));
            float s0 = a0 ? sc0[i] * scale : -1e30f;
            float s1 = a1 ? sc1[i] * scale : -1e30f;
            float tmax = fmaxf(s0, s1);
            #pragma unroll
            for (int off = 1; off < 16; off <<= 1)
                tmax = fmaxf(tmax, __shfl_xor(tmax, off));
            float mnew = fmaxf(m[i], tmax);
            float p0 = expf(s0 - mnew);
            float p1 = expf(s1 - mnew);
            float ps = p0 + p1;
            #pragma unroll
            for (int off = 1; off < 16; off <<= 1)
                ps += __shfl_xor(ps, off);
            alpha[i] = expf(m[i] - mnew);
            l[i] = l[i] * alpha[i] + ps;
            m[i] = mnew;
            Ps[qg + 16*i][tk]      = p0;
            Ps[qg + 16*i][tk + 16] = p1;
        }
        // Ps rows {qg+16i}: written & read only by this wave's 16-lane qg-group.

        #pragma unroll
        for (int i = 0; i < 4; i++) {
            float a = alpha[i];
            #pragma unroll
            for (int d = 0; d < 8; d++) o[i][d] *= a;
        }
        #pragma unroll 2
        for (int j4 = 0; j4 < 8; j4++) {
            float4 p4[4];
            #pragma unroll
            for (int i = 0; i < 4; i++)
                p4[i] = *(const float4*)&Ps[qg + 16*i][j4*4];
            #pragma unroll
            for (int jj = 0; jj < 4; jj++) {
                float4 va = *(const float4*)&Vs[j4*4 + jj][tk*4];
                float4 vb = *(const float4*)&Vs[j4*4 + jj][64 + tk*4];
                #pragma unroll
                for (int i = 0; i < 4; i++) {
                    const float* pp = (const float*)&p4[i];
                    float p = pp[jj];
                    o[i][0] = fmaf(p, va.x, o[i][0]);
                    o[i][1] = fmaf(p, va.y, o[i][1]);
                    o[i][2] = fmaf(p, va.z, o[i][2]);
                    o[i][3] = fmaf(p, va.w, o[i][3]);
                    o[i][4] = fmaf(p, vb.x, o[i][4]);
                    o[i][5] = fmaf(p, vb.y, o[i][5]);
                    o[i][6] = fmaf(p, vb.z, o[i][6]);
                    o[i][7] = fmaf(p, vb.w, o[i][7]);
                }
            }
        }

        if (first) { kt = ktlo; first = false; } else { kt++; }
        if (kt > kthi) break;
    }

    // ---- write Yh/Yl (bf16 split) at [b*4096+s][h*128 + d] ----
    #pragma unroll
    for (int i = 0; i < 4; i++) {
        int row = qg + 16*i;
        float inv = 1.0f / l[i];
        size_t base = ((size_t)b * S_LEN + qs + row) * EMB + h * HD;
        {
            float v0 = o[i][0]*inv, v1 = o[i][1]*inv, v2 = o[i][2]*inv, v3 = o[i][3]*inv;
            unsigned short h0 = f2bf(v0), h1 = f2bf(v1), h2 = f2bf(v2), h3 = f2bf(v3);
            *(short4*)(Yh + base + tk*4) = make_short4((short)h0,(short)h1,(short)h2,(short)h3);
            *(short4*)(Yl + base + tk*4) = make_short4(
                (short)f2bf(v0 - bf2f(h0)), (short)f2bf(v1 - bf2f(h1)),
                (short)f2bf(v2 - bf2f(h2)), (short)f2bf(v3 - bf2f(h3)));
        }
        {
            float v0 = o[i][4]*inv, v1 = o[i][5]*inv, v2 = o[i][6]*inv, v3 = o[i][7]*inv;
            unsigned short h0 = f2bf(v0), h1 = f2bf(v1), h2 = f2bf(v2), h3 = f2bf(v3);
            *(short4*)(Yh + base + 64 + tk*4) = make_short4((short)h0,(short)h1,(short)h2,(short)h3);
            *(short4*)(Yl + base + 64 + tk*4) = make_short4(
                (short)f2bf(v0 - bf2f(h0)), (short)f2bf(v1 - bf2f(h1)),
                (short)f2bf(v2 - bf2f(h2)), (short)f2bf(v3 - bf2f(h3)));
        }
    }
}

// ---------------------------------------------------------------------------
extern "C" void kernel_launch(void* const* d_in, const int* in_sizes, int n_in,
                              void* d_out, int out_size, void* d_ws, size_t ws_size,
                              hipStream_t stream)
{
    const float* x   = (const float*)d_in[0];
    const float* Wq  = (const float*)d_in[1];
    const float* bq  = (const float*)d_in[2];
    const float* Wkv = (const float*)d_in[3];
    const float* bkv = (const float*)d_in[4];
    const float* Wo  = (const float*)d_in[5];
    const float* bo  = (const float*)d_in[6];
    float* out = (float*)d_out;

    // workspace layout — peak 186 MB.
    // Wo^T hi/lo (16 MB) aliases Qr's region: Qr is dead after attn_k, and
    // wsplit_t_k(Wo) launches after attn_k in stream order.
    char* p = (char*)d_ws;
    float* Qr  = (float*)p; p += (size_t)16777216 * 4;   // [B*NH*S][128]  64 MB
    float* Kr  = (float*)p; p += (size_t)4194304  * 4;   // 16 MB
    float* Vr  = (float*)p; p += (size_t)4194304  * 4;   // 16 MB
    short* xh  = (short*)p; p += (size_t)16777216 * 2;   // x hi (later Yh) 32 MB
    short* xl  = (short*)p; p += (size_t)16777216 * 2;   // x lo (later Yl) 32 MB
    short* wqh = (short*)p; p += (size_t)4194304  * 2;   // Wq^T hi  8 MB
    short* wql = (short*)p; p += (size_t)4194304  * 2;   // Wq^T lo  8 MB
    short* wkh = (short*)p; p += (size_t)2097152  * 2;   // Wkv^T hi 4 MB
    short* wkl = (short*)p; p += (size_t)2097152  * 2;   // Wkv^T lo 4 MB
    float* tabc = (float*)p; p += (size_t)262144 * 4;    // cos 1 MB
    float* tabs = (float*)p; p += (size_t)262144 * 4;    // sin 1 MB
    short* woh = (short*)Qr;                             // alias (post-attn)
    short* wol = (short*)Qr + (size_t)4194304;           // alias (post-attn)

    rope_tab_k<<<1024, 256, 0, stream>>>(tabc, tabs);
    split2_k<<<16384, 256, 0, stream>>>(x, xh, xl, 4194304);
    wsplit_t_k<<<dim3(64, 64), 256, 0, stream>>>(Wq,  wqh, wql, 2048);
    wsplit_t_k<<<dim3(32, 64), 256, 0, stream>>>(Wkv, wkh, wkl, 1024);

    gemm_mfma<0><<<dim3(16, 64), 256, 0, stream>>>(xh, xl, wqh, wql, bq,
                                                   tabc, tabs, Qr, nullptr);
    gemm_mfma<1><<<dim3(8, 64), 256, 0, stream>>>(xh, xl, wkh, wkl, bkv,
                                                  tabc, tabs, Kr, Vr);
    attn_k<<<dim3(64, 16, 2), 256, 0, stream>>>(Qr, Kr, Vr, xh, xl); // Yh=xh, Yl=xl

    // Wo split into Qr's (now dead) region, then output projection.
    wsplit_t_k<<<dim3(64, 64), 256, 0, stream>>>(Wo, woh, wol, 2048);
    gemm_mfma<2><<<dim3(16, 64), 256, 0, stream>>>(xh, xl, woh, wol, bo,
                                                   nullptr, nullptr, out, nullptr);
}

// Round 9
// 941.607 us; speedup vs baseline: 5.6497x; 1.6676x over previous
//
#include <hip/hip_runtime.h>
#include <math.h>

// Problem constants
#define S_LEN 4096
#define EMB   2048
#define NH    16
#define NKV   4
#define HD    128
#define WIN   512
#define META  16
#define BATCH 2

typedef __attribute__((ext_vector_type(8))) short sh8;    // 8 bf16 MFMA frag
typedef __attribute__((ext_vector_type(4))) float f32x4;  // MFMA acc frag

__device__ __forceinline__ unsigned short f2bf(float f) {  // fp32 -> bf16 RNE
    unsigned u = __float_as_uint(f);
    return (unsigned short)((u + 0x7FFFu + ((u >> 16) & 1u)) >> 16);
}
__device__ __forceinline__ float bf2f(unsigned short s) {
    return __uint_as_float(((unsigned)s) << 16);
}
__device__ __forceinline__ unsigned packsplit(float v) {   // (hi) | (lo<<16)
    unsigned short h = f2bf(v);
    unsigned short l = f2bf(v - bf2f(h));
    return (unsigned)h | ((unsigned)l << 16);
}
__device__ __forceinline__ sh8 mk8(unsigned a, unsigned b, unsigned c, unsigned d) {
    union { unsigned u[4]; sh8 s; } x;
    x.u[0] = a; x.u[1] = b; x.u[2] = c; x.u[3] = d;
    return x.s;
}

// ---------------------------------------------------------------------------
// RoPE cos/sin table: [4096][64] each.
// ---------------------------------------------------------------------------
__global__ void rope_tab_k(float* __restrict__ tc, float* __restrict__ ts) {
    int idx = blockIdx.x * 256 + threadIdx.x;
    int s = idx >> 6, i = idx & 63;
    float inv = exp2f(-(float)i * 0.2076205059304601f);  // log2(1e4)/64
    float ang = (float)s * inv;
    tc[idx] = cosf(ang);
    ts[idx] = sinf(ang);
}

// ---------------------------------------------------------------------------
// fp32 -> bf16 hi + lo split (same layout)
// ---------------------------------------------------------------------------
__global__ void split2_k(const float* __restrict__ in, short* __restrict__ hi,
                         short* __restrict__ lo, int n4) {
    int idx = blockIdx.x * 256 + threadIdx.x;
    if (idx >= n4) return;
    float4 v = ((const float4*)in)[idx];
    unsigned short h0 = f2bf(v.x), h1 = f2bf(v.y), h2 = f2bf(v.z), h3 = f2bf(v.w);
    short4 h = make_short4((short)h0, (short)h1, (short)h2, (short)h3);
    short4 l = make_short4((short)f2bf(v.x - bf2f(h0)), (short)f2bf(v.y - bf2f(h1)),
                           (short)f2bf(v.z - bf2f(h2)), (short)f2bf(v.w - bf2f(h3)));
    ((short4*)hi)[idx] = h;
    ((short4*)lo)[idx] = l;
}

// ---------------------------------------------------------------------------
// W [K=2048][N] fp32 -> Wt hi/lo bf16 [N][2048] (transpose + split)
// ---------------------------------------------------------------------------
__global__ void wsplit_t_k(const float* __restrict__ W, short* __restrict__ Th,
                           short* __restrict__ Tl, int N) {
    __shared__ float tile[32][33];
    int tx = threadIdx.x & 31, ty = threadIdx.x >> 5;
    int n0 = blockIdx.x * 32, k0 = blockIdx.y * 32;
    #pragma unroll
    for (int j = 0; j < 4; j++)
        tile[ty + 8*j][tx] = W[(size_t)(k0 + ty + 8*j) * N + n0 + tx];
    __syncthreads();
    #pragma unroll
    for (int j = 0; j < 4; j++) {
        int nn = ty + 8*j;
        float v = tile[tx][nn];
        unsigned short h = f2bf(v);
        size_t o = (size_t)(n0 + nn) * 2048 + k0 + tx;
        Th[o] = (short)h;
        Tl[o] = (short)f2bf(v - bf2f(h));
    }
}

// ---------------------------------------------------------------------------
// Vp u32 [(bkv)*4096+s][128] -> Vt u32 [(bkv)*128+d][4096]   (u32 transpose)
// ---------------------------------------------------------------------------
__global__ void vtrans_k(const unsigned* __restrict__ in, unsigned* __restrict__ out) {
    __shared__ unsigned tile[32][33];
    int tx = threadIdx.x & 31, ty = threadIdx.x >> 5;
    int s0 = blockIdx.x * 32;
    int d0 = blockIdx.y * 32;
    int bkv = blockIdx.z;
    const unsigned* ip = in + (size_t)bkv * S_LEN * HD;
    unsigned* op = out + (size_t)bkv * HD * S_LEN;
    #pragma unroll
    for (int j = 0; j < 4; j++)
        tile[ty + 8*j][tx] = ip[(size_t)(s0 + ty + 8*j) * HD + d0 + tx];
    __syncthreads();
    #pragma unroll
    for (int j = 0; j < 4; j++)
        op[(size_t)(d0 + ty + 8*j) * S_LEN + s0 + tx] = tile[tx][ty + 8*j];
}

// ---------------------------------------------------------------------------
// Split-bf16 MFMA GEMM (hardware-verified R8 core), new epilogues:
// MODE 0: +RoPE, *scale -> Qh/Ql bf16 [(b*16+h)*4096+s][128]
// MODE 1: cols<512: K +RoPE -> Kh/Kl bf16 [(b*4+kvh)*4096+s][128]
//         cols>=512: V -> packed u32 (hi|lo<<16) [(b*4+kvh)*4096+s][128]
// MODE 2: plain fp32 -> out
// ---------------------------------------------------------------------------
template<int MODE>
__global__ __launch_bounds__(256)
void gemm_mfma(const short* __restrict__ Ah, const short* __restrict__ Al,
               const short* __restrict__ Bh, const short* __restrict__ Bl,
               const float* __restrict__ bias,
               const float* __restrict__ tabc, const float* __restrict__ tabs,
               void* o0, void* o1, void* o2)
{
    __shared__ sh8 AsH[512], AsL[512], BsH[512], BsL[512];

    const int tid  = threadIdx.x;
    const int row0 = blockIdx.y * 128, col0 = blockIdx.x * 128;
    const int lane = tid & 63, wid = tid >> 6;
    const int wr = wid >> 1, wc = wid & 1;
    const int l15 = lane & 15, kb = lane >> 4;

    f32x4 acc[4][4];
    #pragma unroll
    for (int i = 0; i < 4; i++)
        #pragma unroll
        for (int j = 0; j < 4; j++) acc[i][j] = (f32x4){0.f, 0.f, 0.f, 0.f};

    const int jc = tid & 3;
    const int rr = tid >> 2;
    const int slot0 = rr * 4 + (jc ^ (rr & 3));
    const int slot1 = (rr + 64) * 4 + (jc ^ (rr & 3));

    #pragma unroll 1
    for (int kt = 0; kt < 2048; kt += 32) {
        size_t a0 = (size_t)(row0 + rr) * 2048 + kt + jc * 8;
        size_t a1 = a0 + (size_t)64 * 2048;
        size_t b0 = (size_t)(col0 + rr) * 2048 + kt + jc * 8;
        size_t b1 = b0 + (size_t)64 * 2048;
        sh8 vA0h = *(const sh8*)(Ah + a0);
        sh8 vA0l = *(const sh8*)(Al + a0);
        sh8 vA1h = *(const sh8*)(Ah + a1);
        sh8 vA1l = *(const sh8*)(Al + a1);
        sh8 vB0h = *(const sh8*)(Bh + b0);
        sh8 vB0l = *(const sh8*)(Bl + b0);
        sh8 vB1h = *(const sh8*)(Bh + b1);
        sh8 vB1l = *(const sh8*)(Bl + b1);
        __syncthreads();
        AsH[slot0] = vA0h; AsL[slot0] = vA0l;
        AsH[slot1] = vA1h; AsL[slot1] = vA1l;
        BsH[slot0] = vB0h; BsL[slot0] = vB0l;
        BsH[slot1] = vB1h; BsL[slot1] = vB1l;
        __syncthreads();

        sh8 fah[4], fal[4], fbh[4], fbl[4];
        #pragma unroll
        for (int i = 0; i < 4; i++) {
            int r  = wr * 64 + i * 16 + l15;
            int sl = r * 4 + (kb ^ (r & 3));
            fah[i] = AsH[sl]; fal[i] = AsL[sl];
            r  = wc * 64 + i * 16 + l15;
            sl = r * 4 + (kb ^ (r & 3));
            fbh[i] = BsH[sl]; fbl[i] = BsL[sl];
        }
        #pragma unroll
        for (int i = 0; i < 4; i++)
            #pragma unroll
            for (int j = 0; j < 4; j++) {
                acc[i][j] = __builtin_amdgcn_mfma_f32_16x16x32_bf16(fah[i], fbh[j], acc[i][j], 0, 0, 0);
                acc[i][j] = __builtin_amdgcn_mfma_f32_16x16x32_bf16(fah[i], fbl[j], acc[i][j], 0, 0, 0);
                acc[i][j] = __builtin_amdgcn_mfma_f32_16x16x32_bf16(fal[i], fbh[j], acc[i][j], 0, 0, 0);
            }
    }

    // epilogue: C/D map col = lane&15, row = (lane>>4)*4 + e (hardware-verified R8)
    const int gr_b = row0 + wr * 64 + (kb << 2);
    const int gc_b = col0 + wc * 64 + l15;
    #pragma unroll
    for (int i = 0; i < 4; i++) {
        #pragma unroll
        for (int j = 0; j < 4; j++) {
            f32x4 a = acc[i][j];
            const int gc = gc_b + j * 16;
            const float bs = bias[gc];
            #pragma unroll
            for (int e = 0; e < 4; e++) {
                const int gr = gr_b + i * 16 + e;
                float v = a[e] + bs;
                if (MODE == 2) {
                    ((float*)o0)[(size_t)gr * 2048 + gc] = v;
                } else {
                    const int s = gr & 4095, bb = gr >> 12;
                    const int d = gc & 127;
                    if (MODE == 0) {
                        const int ti = (s << 6) + (d >> 1);
                        float cs = tabc[ti], sn = tabs[ti];
                        float pp = __shfl_xor(v, 1);
                        float o = (d & 1) ? fmaf(v, cs, pp * sn) : fmaf(v, cs, -pp * sn);
                        o *= 0.08838834764831845f;      // attn scale folded into Q
                        const int head = gc >> 7;
                        size_t off = ((size_t)(bb * 16 + head) * 4096 + s) * 128 + d;
                        unsigned short hh = f2bf(o);
                        ((short*)o0)[off] = (short)hh;
                        ((short*)o1)[off] = (short)f2bf(o - bf2f(hh));
                    } else {                  // MODE 1
                        if (gc < 512) {       // K (+RoPE)
                            const int ti = (s << 6) + (d >> 1);
                            float cs = tabc[ti], sn = tabs[ti];
                            float pp = __shfl_xor(v, 1);
                            float o = (d & 1) ? fmaf(v, cs, pp * sn) : fmaf(v, cs, -pp * sn);
                            const int kvh = gc >> 7;
                            size_t off = ((size_t)(bb * 4 + kvh) * 4096 + s) * 128 + d;
                            unsigned short hh = f2bf(o);
                            ((short*)o0)[off] = (short)hh;
                            ((short*)o1)[off] = (short)f2bf(o - bf2f(hh));
                        } else {              // V (packed u32)
                            const int kvh = (gc >> 7) & 3;
                            size_t off = ((size_t)(bb * 4 + kvh) * 4096 + s) * 128 + d;
                            ((unsigned*)o2)[off] = packsplit(v);
                        }
                    }
                }
            }
        }
    }
}

// ---------------------------------------------------------------------------
// MFMA flash attention. Grid (S/128=32, NH, B), 256 thr = 4 waves x 32 q.
// Q frags in registers; K [32k][128d] bf16 hi/lo LDS (chunk XOR swizzle);
// V^T [128d][32k] packed u32 LDS (pitch 36); P via per-wave LDS (pitch 36).
// Split-bf16 3-product for both QK^T and PV. Scale pre-folded into Q.
// ---------------------------------------------------------------------------
__global__ __launch_bounds__(256, 2)
void attn_k(const short* __restrict__ Qh, const short* __restrict__ Ql,
            const short* __restrict__ Kh, const short* __restrict__ Kl,
            const unsigned* __restrict__ Vt,
            short* __restrict__ Yh, short* __restrict__ Yl)
{
    __shared__ sh8 KsH[512], KsL[512];     // [32 rows][16 chunks], chunk ^= row&7
    __shared__ unsigned Vts[128 * 36];     // [d][k] packed hi|lo<<16, pitch 36
    __shared__ unsigned Ps[4 * 1152];      // per-wave [32 q][36]

    const int tid  = threadIdx.x;
    const int w    = tid >> 6, lane = tid & 63;
    const int g    = lane >> 4, c = lane & 15;
    const int qs   = blockIdx.x * 128;
    const int h    = blockIdx.y, b = blockIdx.z;
    const int kvh  = h >> 2;
    const size_t qhead = (size_t)(b * NH + h) * S_LEN;
    const size_t kvbK  = (size_t)(b * NKV + kvh) * S_LEN;
    const size_t kvbV  = (size_t)(b * NKV + kvh) * HD;

    // Q fragments (A-layout): lane&15 = q row, elems = 8 consecutive d
    sh8 qa[2][4][2];
    #pragma unroll
    for (int qf = 0; qf < 2; qf++)
        #pragma unroll
        for (int ds = 0; ds < 4; ds++) {
            size_t off = (qhead + qs + w * 32 + qf * 16 + c) * HD + ds * 32 + 8 * g;
            qa[qf][ds][0] = *(const sh8*)(Qh + off);
            qa[qf][ds][1] = *(const sh8*)(Ql + off);
        }

    f32x4 acc[2][8];
    float mrow[8], lrow[8];
    #pragma unroll
    for (int qf = 0; qf < 2; qf++)
        #pragma unroll
        for (int df = 0; df < 8; df++) acc[qf][df] = (f32x4){0.f, 0.f, 0.f, 0.f};
    #pragma unroll
    for (int r = 0; r < 8; r++) { mrow[r] = -1e30f; lrow[r] = 0.f; }

    int ktlo = ((qs - WIN + 1) < 32) ? 1 : ((qs - WIN + 1) >> 5);
    const int kthi = (qs >> 5) + 3;
    unsigned* const pbase = &Ps[w * 1152];

    int kt = 0;
    bool first = true;
    while (1) {
        const int kb = kt * 32;
        __syncthreads();     // all waves done with prev K/V LDS
        // ---- stage K tile (bf16 hi/lo, swizzled chunks) ----
        #pragma unroll
        for (int i = 0; i < 2; i++) {
            int fid = tid + 256 * i;
            int row = fid >> 4, cc = fid & 15;
            size_t ga = (kvbK + kb + row) * HD + cc * 8;
            int slot = row * 16 + (cc ^ (row & 7));
            KsH[slot] = *(const sh8*)(Kh + ga);
            KsL[slot] = *(const sh8*)(Kl + ga);
        }
        // ---- stage V^T tile (u32 copy, no VALU) ----
        #pragma unroll
        for (int i = 0; i < 4; i++) {
            int fid = tid + 256 * i;
            int d = fid >> 3, kc = fid & 7;
            uint4 vv = *(const uint4*)(Vt + (kvbV + d) * S_LEN + kb + kc * 4);
            *(uint4*)&Vts[d * 36 + kc * 4] = vv;
        }
        __syncthreads();

        const bool waveskip = (kb > qs + w * 32 + 31);   // fully causal-masked for this wave
        if (!waveskip) {
            // ---- QK^T: S[32q][32k] via split-bf16 ----
            f32x4 s[2][2];
            #pragma unroll
            for (int qf = 0; qf < 2; qf++)
                #pragma unroll
                for (int kf = 0; kf < 2; kf++) s[qf][kf] = (f32x4){0.f, 0.f, 0.f, 0.f};
            #pragma unroll
            for (int ds = 0; ds < 4; ds++) {
                int r0 = c,      sl0 = r0 * 16 + ((ds * 4 + g) ^ (r0 & 7));
                int r1 = 16 + c, sl1 = r1 * 16 + ((ds * 4 + g) ^ (r1 & 7));
                sh8 kh0 = KsH[sl0], kl0 = KsL[sl0];
                sh8 kh1 = KsH[sl1], kl1 = KsL[sl1];
                #pragma unroll
                for (int qf = 0; qf < 2; qf++) {
                    s[qf][0] = __builtin_amdgcn_mfma_f32_16x16x32_bf16(qa[qf][ds][0], kh0, s[qf][0], 0, 0, 0);
                    s[qf][0] = __builtin_amdgcn_mfma_f32_16x16x32_bf16(qa[qf][ds][0], kl0, s[qf][0], 0, 0, 0);
                    s[qf][0] = __builtin_amdgcn_mfma_f32_16x16x32_bf16(qa[qf][ds][1], kh0, s[qf][0], 0, 0, 0);
                    s[qf][1] = __builtin_amdgcn_mfma_f32_16x16x32_bf16(qa[qf][ds][0], kh1, s[qf][1], 0, 0, 0);
                    s[qf][1] = __builtin_amdgcn_mfma_f32_16x16x32_bf16(qa[qf][ds][0], kl1, s[qf][1], 0, 0, 0);
                    s[qf][1] = __builtin_amdgcn_mfma_f32_16x16x32_bf16(qa[qf][ds][1], kh1, s[qf][1], 0, 0, 0);
                }
            }

            // ---- mask (edge tiles only; scale already folded into Q) ----
            bool interior = (kt != 0) && (kb + 31 <= qs) && (kb >= qs - 384);
            if (!interior) {
                #pragma unroll
                for (int qf = 0; qf < 2; qf++)
                    #pragma unroll
                    for (int kf = 0; kf < 2; kf++) {
                        int kp = kb + kf * 16 + c;
                        #pragma unroll
                        for (int e = 0; e < 4; e++) {
                            int qp = qs + w * 32 + qf * 16 + 4 * g + e;
                            bool ok = (kp <= qp) && ((kp >= qp - (WIN - 1)) || (kp < META));
                            if (!ok) s[qf][kf][e] = -3e38f;
                        }
                    }
            }

            // ---- online softmax (rows lane-replicated over 16 key-lanes) ----
            unsigned pw[2][2][4];
            float alpha[8];
            #pragma unroll
            for (int qf = 0; qf < 2; qf++)
                #pragma unroll
                for (int e = 0; e < 4; e++) {
                    int r = qf * 4 + e;
                    float tmax = fmaxf(s[qf][0][e], s[qf][1][e]);
                    tmax = fmaxf(tmax, __shfl_xor(tmax, 1));
                    tmax = fmaxf(tmax, __shfl_xor(tmax, 2));
                    tmax = fmaxf(tmax, __shfl_xor(tmax, 4));
                    tmax = fmaxf(tmax, __shfl_xor(tmax, 8));
                    float mnew = fmaxf(mrow[r], tmax);
                    float a  = __expf(mrow[r] - mnew);
                    float p0 = __expf(s[qf][0][e] - mnew);
                    float p1 = __expf(s[qf][1][e] - mnew);
                    mrow[r] = mnew;
                    lrow[r] = lrow[r] * a + p0 + p1;   // cross-lane reduce deferred
                    alpha[r] = a;
                    pw[qf][0][e] = packsplit(p0);
                    pw[qf][1][e] = packsplit(p1);
                }
            #pragma unroll
            for (int qf = 0; qf < 2; qf++)
                #pragma unroll
                for (int df = 0; df < 8; df++)
                    #pragma unroll
                    for (int e = 0; e < 4; e++)
                        acc[qf][df][e] *= alpha[qf * 4 + e];

            // ---- P: D-layout -> A-layout through wave-private LDS ----
            #pragma unroll
            for (int qf = 0; qf < 2; qf++)
                #pragma unroll
                for (int kf = 0; kf < 2; kf++)
                    #pragma unroll
                    for (int e = 0; e < 4; e++)
                        pbase[(qf * 16 + 4 * g + e) * 36 + kf * 16 + c] = pw[qf][kf][e];

            sh8 ph[2], pl[2];
            #pragma unroll
            for (int qf = 0; qf < 2; qf++) {
                uint4 a0 = *(const uint4*)&pbase[(qf * 16 + c) * 36 + 8 * g];
                uint4 a1 = *(const uint4*)&pbase[(qf * 16 + c) * 36 + 8 * g + 4];
                ph[qf] = mk8((a0.x & 0xFFFFu) | (a0.y << 16), (a0.z & 0xFFFFu) | (a0.w << 16),
                             (a1.x & 0xFFFFu) | (a1.y << 16), (a1.z & 0xFFFFu) | (a1.w << 16));
                pl[qf] = mk8((a0.x >> 16) | (a0.y & 0xFFFF0000u), (a0.z >> 16) | (a0.w & 0xFFFF0000u),
                             (a1.x >> 16) | (a1.y & 0xFFFF0000u), (a1.z >> 16) | (a1.w & 0xFFFF0000u));
            }

            // ---- PV: O[32q][128d] via split-bf16 ----
            #pragma unroll
            for (int df = 0; df < 8; df++) {
                int d = df * 16 + c;
                uint4 b0 = *(const uint4*)&Vts[d * 36 + 8 * g];
                uint4 b1 = *(const uint4*)&Vts[d * 36 + 8 * g + 4];
                sh8 vh = mk8((b0.x & 0xFFFFu) | (b0.y << 16), (b0.z & 0xFFFFu) | (b0.w << 16),
                             (b1.x & 0xFFFFu) | (b1.y << 16), (b1.z & 0xFFFFu) | (b1.w << 16));
                sh8 vl = mk8((b0.x >> 16) | (b0.y & 0xFFFF0000u), (b0.z >> 16) | (b0.w & 0xFFFF0000u),
                             (b1.x >> 16) | (b1.y & 0xFFFF0000u), (b1.z >> 16) | (b1.w & 0xFFFF0000u));
                #pragma unroll
                for (int qf = 0; qf < 2; qf++) {
                    acc[qf][df] = __builtin_amdgcn_mfma_f32_16x16x32_bf16(ph[qf], vh, acc[qf][df], 0, 0, 0);
                    acc[qf][df] = __builtin_amdgcn_mfma_f32_16x16x32_bf16(ph[qf], vl, acc[qf][df], 0, 0, 0);
                    acc[qf][df] = __builtin_amdgcn_mfma_f32_16x16x32_bf16(pl[qf], vh, acc[qf][df], 0, 0, 0);
                }
            }
        }

        if (first) { kt = ktlo; first = false; } else { kt++; }
        if (kt > kthi) break;
    }

    // ---- final l reduce, normalize, transpose-dump, bf16-split write ----
    #pragma unroll
    for (int r = 0; r < 8; r++) {
        float l = lrow[r];
        l += __shfl_xor(l, 1);
        l += __shfl_xor(l, 2);
        l += __shfl_xor(l, 4);
        l += __shfl_xor(l, 8);
        lrow[r] = 1.0f / l;
    }

    float* scr = (float*)pbase;        // per-wave scratch (>= 4*132 floats)
    #pragma unroll
    for (int qf = 0; qf < 2; qf++)
        #pragma unroll
        for (int e = 0; e < 4; e++) {
            float inv = lrow[qf * 4 + e];
            #pragma unroll
            for (int df = 0; df < 8; df++)
                scr[g * 132 + df * 16 + c] = acc[qf][df][e] * inv;
            // wave-synchronous LDS: same-wave ds ops are program-ordered
            float o[8];
            #pragma unroll
            for (int j = 0; j < 2; j++) {
                float4 t = *(const float4*)&scr[g * 132 + c * 8 + j * 4];
                o[j * 4 + 0] = t.x; o[j * 4 + 1] = t.y;
                o[j * 4 + 2] = t.z; o[j * 4 + 3] = t.w;
            }
            unsigned hw[4], lw[4];
            #pragma unroll
            for (int j = 0; j < 4; j++) {
                unsigned short h0 = f2bf(o[2 * j]), h1 = f2bf(o[2 * j + 1]);
                hw[j] = (unsigned)h0 | ((unsigned)h1 << 16);
                lw[j] = (unsigned)f2bf(o[2 * j] - bf2f(h0)) |
                        ((unsigned)f2bf(o[2 * j + 1] - bf2f(h1)) << 16);
            }
            int qrow = qs + w * 32 + qf * 16 + 4 * g + e;
            size_t yoff = ((size_t)(b * S_LEN) + qrow) * EMB + h * HD + c * 8;
            *(uint4*)(Yh + yoff) = make_uint4(hw[0], hw[1], hw[2], hw[3]);
            *(uint4*)(Yl + yoff) = make_uint4(lw[0], lw[1], lw[2], lw[3]);
        }
}

// ---------------------------------------------------------------------------
extern "C" void kernel_launch(void* const* d_in, const int* in_sizes, int n_in,
                              void* d_out, int out_size, void* d_ws, size_t ws_size,
                              hipStream_t stream)
{
    const float* x   = (const float*)d_in[0];
    const float* Wq  = (const float*)d_in[1];
    const float* bq  = (const float*)d_in[2];
    const float* Wkv = (const float*)d_in[3];
    const float* bkv = (const float*)d_in[4];
    const float* Wo  = (const float*)d_in[5];
    const float* bo  = (const float*)d_in[6];
    float* out = (float*)d_out;

    // workspace — 186 MiB peak (same as validated R8 layout).
    const size_t M32 = 33554432;   // 32 MiB
    char* p = (char*)d_ws;
    short*    xh   = (short*)p;                            // x hi (later Yh)
    short*    xl   = (short*)(p + M32);                    // x lo (later Yl)
    short*    Qhb  = (short*)(p + 2 * M32);                // Q hi bf16
    short*    Qlb  = (short*)(p + 3 * M32);                // Q lo bf16
    short*    Khb  = (short*)(p + 4 * M32);                // K hi (8 MiB)
    short*    Klb  = (short*)(p + 4 * M32 + 8388608);      // K lo (8 MiB)
    unsigned* VtHL = (unsigned*)(p + 4 * M32 + 16777216);  // V^T packed (16 MiB)
    char*     WA   = p + 4 * M32 + 33554432;               // 16 MiB region: wq | Vp | wo
    char*     WB   = WA + 16777216;                        // 8 MiB region: wkv
    float*    tabc = (float*)(WB + 8388608);
    float*    tabs = tabc + 262144;

    short*    wqh = (short*)WA;  short* wql = wqh + 4194304;
    unsigned* VpHL = (unsigned*)WA;                        // after gemm<0>
    short*    woh = (short*)WA;  short* wol = woh + 4194304; // after vtrans
    short*    wkh = (short*)WB;  short* wkl = wkh + 2097152;

    rope_tab_k<<<1024, 256, 0, stream>>>(tabc, tabs);
    split2_k<<<16384, 256, 0, stream>>>(x, xh, xl, 4194304);
    wsplit_t_k<<<dim3(64, 64), 256, 0, stream>>>(Wq, wqh, wql, 2048);
    gemm_mfma<0><<<dim3(16, 64), 256, 0, stream>>>(xh, xl, wqh, wql, bq,
                                                   tabc, tabs, Qhb, Qlb, nullptr);
    wsplit_t_k<<<dim3(32, 64), 256, 0, stream>>>(Wkv, wkh, wkl, 1024);   // reuses nothing live
    gemm_mfma<1><<<dim3(8, 64), 256, 0, stream>>>(xh, xl, wkh, wkl, bkv,
                                                  tabc, tabs, Khb, Klb, VpHL);
    vtrans_k<<<dim3(128, 4, 8), 256, 0, stream>>>(VpHL, VtHL);
    attn_k<<<dim3(32, 16, 2), 256, 0, stream>>>(Qhb, Qlb, Khb, Klb, VtHL, xh, xl);
    wsplit_t_k<<<dim3(64, 64), 256, 0, stream>>>(Wo, woh, wol, 2048);    // into WA (Vp dead)
    gemm_mfma<2><<<dim3(16, 64), 256, 0, stream>>>(xh, xl, woh, wol, bo,
                                                   nullptr, nullptr, out, nullptr, nullptr);
}